// Round 1
// baseline (696.736 us; speedup 1.0000x reference)
//
#include <hip/hip_runtime.h>
#include <hip/hip_bf16.h>

#define NF 40960
#define MD 256
#define BATCH 2048
#define CAP 512

__device__ __forceinline__ float clip01(float v) {
    return fminf(fmaxf(v, 0.0f), 1.0f);
}

// ft_w [256, 40960] row-major  ->  ftT [40960, 256] row-major
__global__ __launch_bounds__(256) void transpose_ft(const float* __restrict__ in,
                                                    float* __restrict__ outT) {
    __shared__ float tile[32][33];
    const int f0 = blockIdx.x * 32;
    const int m0 = blockIdx.y * 32;
    const int tx = threadIdx.x;      // 0..31
    const int ty = threadIdx.y;      // 0..7
    #pragma unroll
    for (int r = 0; r < 32; r += 8)
        tile[ty + r][tx] = in[(size_t)(m0 + ty + r) * NF + f0 + tx];
    __syncthreads();
    #pragma unroll
    for (int r = 0; r < 32; r += 8)
        outT[(size_t)(f0 + ty + r) * MD + m0 + tx] = tile[tx][ty + r];
}

__global__ __launch_bounds__(256) void nnue_main(
    const float* __restrict__ wf, const float* __restrict__ bfeat,
    const float* __restrict__ stm, const float* __restrict__ ft,
    const float* __restrict__ ft_b,
    const float* __restrict__ l1_w, const float* __restrict__ l1_b,
    const float* __restrict__ l2_w, const float* __restrict__ l2_b,
    const float* __restrict__ l3_w, const float* __restrict__ l3_b,
    float* __restrict__ out, int transposed)
{
    __shared__ int idxW[CAP];
    __shared__ int idxB[CAP];
    __shared__ int nW, nB;
    __shared__ float xsh[512];
    __shared__ float red[32][9];   // 9: conflict-free (odd stride)
    __shared__ float ysh[32], zsh[32];

    const int pos = blockIdx.x;
    const int t = threadIdx.x;

    if (t == 0) { nW = 0; nB = 0; }
    __syncthreads();

    // ---- phase 1: scan both feature rows (coalesced float4), compact nonzeros
    const float4* wf4 = (const float4*)(wf + (size_t)pos * NF);
    const float4* bf4 = (const float4*)(bfeat + (size_t)pos * NF);
    #pragma unroll 4
    for (int i = t; i < NF / 4; i += 256) {
        float4 v = wf4[i];
        if (v.x != 0.0f) { int p = atomicAdd(&nW, 1); if (p < CAP) idxW[p] = 4 * i + 0; }
        if (v.y != 0.0f) { int p = atomicAdd(&nW, 1); if (p < CAP) idxW[p] = 4 * i + 1; }
        if (v.z != 0.0f) { int p = atomicAdd(&nW, 1); if (p < CAP) idxW[p] = 4 * i + 2; }
        if (v.w != 0.0f) { int p = atomicAdd(&nW, 1); if (p < CAP) idxW[p] = 4 * i + 3; }
        float4 u = bf4[i];
        if (u.x != 0.0f) { int p = atomicAdd(&nB, 1); if (p < CAP) idxB[p] = 4 * i + 0; }
        if (u.y != 0.0f) { int p = atomicAdd(&nB, 1); if (p < CAP) idxB[p] = 4 * i + 1; }
        if (u.z != 0.0f) { int p = atomicAdd(&nB, 1); if (p < CAP) idxB[p] = 4 * i + 2; }
        if (u.w != 0.0f) { int p = atomicAdd(&nB, 1); if (p < CAP) idxB[p] = 4 * i + 3; }
    }
    __syncthreads();

    const int cw = min(nW, CAP);
    const int cb = min(nB, CAP);

    // ---- phase 2: accumulate ft rows; thread t owns output channel m = t
    float accW = ft_b[t];
    float accB = ft_b[t];
    if (transposed) {
        for (int j = 0; j < cw; ++j) accW += ft[(size_t)idxW[j] * MD + t];
        for (int j = 0; j < cb; ++j) accB += ft[(size_t)idxB[j] * MD + t];
    } else {
        const float* row = ft + (size_t)t * NF;   // slow fallback: strided
        for (int j = 0; j < cw; ++j) accW += row[idxW[j]];
        for (int j = 0; j < cb; ++j) accB += row[idxB[j]];
    }

    // ---- stm perspective select + clip -> x[512]
    const float s = stm[pos];
    xsh[t]       = clip01(s * accW + (1.0f - s) * accB);
    xsh[256 + t] = clip01(s * accB + (1.0f - s) * accW);
    __syncthreads();

    // ---- L1: y[n] = clip(sum_512 x[j]*l1_w[n][j] + b, 0, 1)
    // layout: n = t&31 (broadcast LDS reads within wave), chunk c = t>>5 (8 chunks of 64)
    {
        const int n = t & 31;
        const int c = t >> 5;
        const float* w1 = l1_w + (size_t)n * 512 + c * 64;
        const float* xx = xsh + c * 64;
        float p = 0.0f;
        #pragma unroll
        for (int j = 0; j < 64; ++j) p += xx[j] * w1[j];
        red[n][c] = p;
    }
    __syncthreads();
    if (t < 32) {
        float v = l1_b[t];
        #pragma unroll
        for (int c = 0; c < 8; ++c) v += red[t][c];
        ysh[t] = clip01(v);
    }
    __syncthreads();

    // ---- L2: z[k] = clip(sum_32 y[n]*l2_w[k][n] + b, 0, 1)
    if (t < 32) {
        float v = l2_b[t];
        const float* w2 = l2_w + t * 32;
        #pragma unroll
        for (int j = 0; j < 32; ++j) v += ysh[j] * w2[j];
        zsh[t] = clip01(v);
    }
    __syncthreads();

    // ---- L3 + output map
    if (t == 0) {
        float v = l3_b[0];
        #pragma unroll
        for (int j = 0; j < 32; ++j) v += zsh[j] * l3_w[j];
        v = clip01(v);
        out[pos] = (v - 0.5f) * 20000.0f;
    }
}

extern "C" void kernel_launch(void* const* d_in, const int* in_sizes, int n_in,
                              void* d_out, int out_size, void* d_ws, size_t ws_size,
                              hipStream_t stream) {
    const float* wf    = (const float*)d_in[0];
    const float* bfeat = (const float*)d_in[1];
    const float* stm   = (const float*)d_in[2];
    const float* ft_w  = (const float*)d_in[3];
    const float* ft_b  = (const float*)d_in[4];
    const float* l1_w  = (const float*)d_in[5];
    const float* l1_b  = (const float*)d_in[6];
    const float* l2_w  = (const float*)d_in[7];
    const float* l2_b  = (const float*)d_in[8];
    const float* l3_w  = (const float*)d_in[9];
    const float* l3_b  = (const float*)d_in[10];
    float* out = (float*)d_out;

    const size_t needT = (size_t)NF * MD * sizeof(float);
    const int useT = (ws_size >= needT) ? 1 : 0;
    float* ftT = (float*)d_ws;

    if (useT) {
        transpose_ft<<<dim3(NF / 32, MD / 32), dim3(32, 8), 0, stream>>>(ft_w, ftT);
    }
    nnue_main<<<BATCH, 256, 0, stream>>>(
        wf, bfeat, stm, useT ? ftT : ft_w, ft_b,
        l1_w, l1_b, l2_w, l2_b, l3_w, l3_b, out, useT);
}